// Round 1
// baseline (1065.126 us; speedup 1.0000x reference)
//
#include <hip/hip_runtime.h>
#include <math.h>

typedef unsigned short u16;
typedef unsigned int   u32;
typedef __attribute__((ext_vector_type(8))) short short8;
typedef __attribute__((ext_vector_type(4))) float floatx4;
typedef __attribute__((ext_vector_type(4))) u16   u16x4;

#define NE   16      // experts
#define CAP  2048    // capacity per expert
#define HD   2048    // hidden
#define FD   1024    // intermediate
#define NT   4096    // tokens

// ---------- helpers ----------
__device__ __forceinline__ u16 f2bf(float f) {
    u32 u = __builtin_bit_cast(u32, f);
    u = (u + 0x7FFFu + ((u >> 16) & 1u)) >> 16;   // RNE
    return (u16)u;
}

typedef const u32 __attribute__((address_space(1))) glb_u32;
typedef u32 __attribute__((address_space(3)))       lds_u32;

__device__ __forceinline__ void cp16(const void* g, void* l) {
    __builtin_amdgcn_global_load_lds((glb_u32*)g, (lds_u32*)l, 16, 0, 0);
}

__device__ __forceinline__ floatx4 mfma_bf16(short8 a, short8 b, floatx4 c) {
    return __builtin_amdgcn_mfma_f32_16x16x32_bf16(a, b, c, 0, 0, 0);
}

// ---------- x -> bf16 ----------
__global__ void cvt_x_kernel(const float* __restrict__ x, u16* __restrict__ xb) {
    int i = blockIdx.x * 256 + threadIdx.x;
    float4 v = reinterpret_cast<const float4*>(x)[i];
    u16x4 o; o.x = f2bf(v.x); o.y = f2bf(v.y); o.z = f2bf(v.z); o.w = f2bf(v.w);
    reinterpret_cast<u16x4*>(xb)[i] = o;
}

// ---------- transpose + convert: in [R][Cc] fp32 -> out [Cc][R] bf16 (per expert) ----------
__global__ void transpose_cvt(const float* __restrict__ in, u16* __restrict__ out,
                              int R, int Cc) {
    __shared__ u16 tile[64][65];
    int e = blockIdx.y;
    int tilesC = Cc >> 6;
    int tr = blockIdx.x / tilesC;
    int tc = blockIdx.x - tr * tilesC;
    const float* ip = in + (size_t)e * R * Cc + (size_t)(tr * 64) * Cc + tc * 64;
    u16* op = out + (size_t)e * R * Cc + (size_t)(tc * 64) * R + tr * 64;
    int c  = threadIdx.x & 63;
    int r0 = threadIdx.x >> 6;
    #pragma unroll
    for (int i = 0; i < 16; ++i) {
        int r = r0 + (i << 2);
        tile[r][c] = f2bf(ip[(size_t)r * Cc + c]);
    }
    __syncthreads();
    int rr = threadIdx.x & 63;
    int c0 = threadIdx.x >> 6;
    #pragma unroll
    for (int i = 0; i < 16; ++i) {
        int cc = c0 + (i << 2);
        op[(size_t)cc * R + rr] = tile[rr][cc];
    }
}

// ---------- router: fp64-exact logits, top-4, softmax, dispatch ----------
__global__ void router_kernel(const float* __restrict__ x, const float* __restrict__ gw,
                              float* __restrict__ logits, int* __restrict__ tok,
                              float* __restrict__ wts, int* __restrict__ cnt) {
    int t = blockIdx.x;
    int l = threadIdx.x;      // 0..63
    const float* xr = x + (size_t)t * HD;
    double acc[NE];
    #pragma unroll
    for (int e = 0; e < NE; ++e) acc[e] = 0.0;
    for (int i = 0; i < HD / 64; ++i) {
        float xv = xr[l + (i << 6)];
        const float* g = gw + (size_t)(l + (i << 6)) * NE;
        #pragma unroll
        for (int e = 0; e < NE; ++e) acc[e] += (double)xv * (double)g[e];
    }
    #pragma unroll
    for (int e = 0; e < NE; ++e) {
        double v = acc[e];
        #pragma unroll
        for (int off = 1; off < 64; off <<= 1) v += __shfl_xor(v, off, 64);
        acc[e] = v;
    }
    if (l == 0) {
        #pragma unroll
        for (int e = 0; e < NE; ++e) logits[(size_t)t * NE + e] = (float)acc[e];
        int bi[4]; double bv[4];
        u32 used = 0;
        for (int k = 0; k < 4; ++k) {
            int best = 0; double bvv = -1e300;
            for (int e = 0; e < NE; ++e)
                if (!((used >> e) & 1u) && acc[e] > bvv) { bvv = acc[e]; best = e; }
            bi[k] = best; bv[k] = bvv; used |= 1u << best;
        }
        double s = 0.0, wv[4];
        for (int k = 0; k < 4; ++k) { wv[k] = exp(bv[k] - bv[0]); s += wv[k]; }
        for (int k = 0; k < 4; ++k) {
            int e = bi[k];
            int pos = atomicAdd(&cnt[e], 1);
            if (pos < CAP) {
                tok[e * CAP + pos] = t;
                wts[e * CAP + pos] = (float)(wv[k] / s);
            }
        }
    }
}

// ---------- GEMM1: fused gate+up, 128x(64+64) tile, BK=64, silu epilogue ----------
__global__ __launch_bounds__(256) void gemm_gateup(
        const u16* __restrict__ xb, const u16* __restrict__ wgT, const u16* __restrict__ wuT,
        const int* __restrict__ tok, const int* __restrict__ cnt, u16* __restrict__ hbuf) {
    int bid = blockIdx.x;
    int e  = bid >> 8;
    int mt = (bid >> 4) & 15;
    int nt = bid & 15;
    int ne = cnt[e]; if (ne > CAP) ne = CAP;
    int row0 = mt << 7;
    if (row0 >= ne) return;

    __shared__ u16 As[128 * 64];
    __shared__ u16 Bg[64 * 64];
    __shared__ u16 Bu[64 * 64];
    __shared__ int toklds[128];

    int tid = threadIdx.x;
    if (tid < 128) {
        int r = row0 + tid;
        toklds[tid] = tok[e * CAP + (r < ne ? r : 0)];
    }
    __syncthreads();

    const u16* asrc[4];
    #pragma unroll
    for (int p = 0; p < 4; ++p) {
        int idx = tid + (p << 8);
        asrc[p] = xb + (size_t)toklds[idx >> 3] * HD + ((idx & 7) << 3);
    }
    const u16* bgb = wgT + ((size_t)e * FD + (nt << 6)) * HD;
    const u16* bub = wuT + ((size_t)e * FD + (nt << 6)) * HD;
    const u16* bgsrc[2]; const u16* busrc[2];
    #pragma unroll
    for (int p = 0; p < 2; ++p) {
        int idx = tid + (p << 8);
        bgsrc[p] = bgb + (size_t)(idx >> 3) * HD + ((idx & 7) << 3);
        busrc[p] = bub + (size_t)(idx >> 3) * HD + ((idx & 7) << 3);
    }

    floatx4 accg[4][2], accu[4][2];
    #pragma unroll
    for (int i = 0; i < 4; ++i)
        #pragma unroll
        for (int j = 0; j < 2; ++j) {
            accg[i][j] = floatx4{0.f, 0.f, 0.f, 0.f};
            accu[i][j] = floatx4{0.f, 0.f, 0.f, 0.f};
        }

    int l = tid & 63, w = tid >> 6;
    int wm = (w >> 1) << 6;   // 0 / 64
    int wn = (w & 1) << 5;    // 0 / 32
    int lr = l & 15, q = l >> 4;

    for (int k0 = 0; k0 < HD; k0 += 64) {
        #pragma unroll
        for (int p = 0; p < 4; ++p) cp16(asrc[p] + k0, &As[(tid + (p << 8)) << 3]);
        #pragma unroll
        for (int p = 0; p < 2; ++p) {
            cp16(bgsrc[p] + k0, &Bg[(tid + (p << 8)) << 3]);
            cp16(busrc[p] + k0, &Bu[(tid + (p << 8)) << 3]);
        }
        __syncthreads();
        #pragma unroll
        for (int kk = 0; kk < 2; ++kk) {
            short8 af[4], bg[2], bu[2];
            #pragma unroll
            for (int mi = 0; mi < 4; ++mi)
                af[mi] = *(const short8*)&As[(wm + mi * 16 + lr) * 64 + kk * 32 + q * 8];
            #pragma unroll
            for (int ni = 0; ni < 2; ++ni) {
                bg[ni] = *(const short8*)&Bg[(wn + ni * 16 + lr) * 64 + kk * 32 + q * 8];
                bu[ni] = *(const short8*)&Bu[(wn + ni * 16 + lr) * 64 + kk * 32 + q * 8];
            }
            #pragma unroll
            for (int mi = 0; mi < 4; ++mi)
                #pragma unroll
                for (int ni = 0; ni < 2; ++ni) {
                    accg[mi][ni] = mfma_bf16(af[mi], bg[ni], accg[mi][ni]);
                    accu[mi][ni] = mfma_bf16(af[mi], bu[ni], accu[mi][ni]);
                }
        }
        __syncthreads();
    }

    // epilogue: h = silu(g)*u, bf16 store
    #pragma unroll
    for (int mi = 0; mi < 4; ++mi) {
        #pragma unroll
        for (int r = 0; r < 4; ++r) {
            int rowl = wm + mi * 16 + q * 4 + r;
            int srow = row0 + rowl;
            if (srow < ne) {
                #pragma unroll
                for (int ni = 0; ni < 2; ++ni) {
                    float g = accg[mi][ni][r], u = accu[mi][ni][r];
                    float hv = g * u / (1.0f + __expf(-g));
                    hbuf[((size_t)e * CAP + srow) * FD + (nt << 6) + wn + ni * 16 + lr] = f2bf(hv);
                }
            }
        }
    }
}

// ---------- GEMM2: down-proj 128x128 tile, BK=64, weighted atomic scatter ----------
__global__ __launch_bounds__(256) void gemm_down(
        const u16* __restrict__ hbuf, const u16* __restrict__ wdT,
        const int* __restrict__ tok, const float* __restrict__ wts,
        const int* __restrict__ cnt, float* __restrict__ y) {
    int bid = blockIdx.x;
    int e  = bid >> 8;
    int mt = (bid >> 4) & 15;
    int nt = bid & 15;
    int ne = cnt[e]; if (ne > CAP) ne = CAP;
    int row0 = mt << 7;
    if (row0 >= ne) return;

    __shared__ u16 As[128 * 64];
    __shared__ u16 Bs[128 * 64];
    __shared__ int   toklds[128];
    __shared__ float wlds[128];

    int tid = threadIdx.x;
    if (tid < 128) {
        int r = row0 + tid;
        int ok = (r < ne);
        toklds[tid] = ok ? tok[e * CAP + r] : 0;
        wlds[tid]  = ok ? wts[e * CAP + r] : 0.0f;
    }

    const u16* ab = hbuf + ((size_t)e * CAP + row0) * FD;
    const u16* bb = wdT + ((size_t)e * HD + (nt << 7)) * FD;
    const u16* asrc[4]; const u16* bsrc[4];
    #pragma unroll
    for (int p = 0; p < 4; ++p) {
        int idx = tid + (p << 8);
        asrc[p] = ab + (size_t)(idx >> 3) * FD + ((idx & 7) << 3);
        bsrc[p] = bb + (size_t)(idx >> 3) * FD + ((idx & 7) << 3);
    }

    floatx4 acc[4][4];
    #pragma unroll
    for (int i = 0; i < 4; ++i)
        #pragma unroll
        for (int j = 0; j < 4; ++j) acc[i][j] = floatx4{0.f, 0.f, 0.f, 0.f};

    int l = tid & 63, w = tid >> 6;
    int wm = (w >> 1) << 6;
    int wn = (w & 1) << 6;
    int lr = l & 15, q = l >> 4;

    for (int k0 = 0; k0 < FD; k0 += 64) {
        #pragma unroll
        for (int p = 0; p < 4; ++p) {
            cp16(asrc[p] + k0, &As[(tid + (p << 8)) << 3]);
            cp16(bsrc[p] + k0, &Bs[(tid + (p << 8)) << 3]);
        }
        __syncthreads();
        #pragma unroll
        for (int kk = 0; kk < 2; ++kk) {
            short8 af[4], bf[4];
            #pragma unroll
            for (int mi = 0; mi < 4; ++mi)
                af[mi] = *(const short8*)&As[(wm + mi * 16 + lr) * 64 + kk * 32 + q * 8];
            #pragma unroll
            for (int ni = 0; ni < 4; ++ni)
                bf[ni] = *(const short8*)&Bs[(wn + ni * 16 + lr) * 64 + kk * 32 + q * 8];
            #pragma unroll
            for (int mi = 0; mi < 4; ++mi)
                #pragma unroll
                for (int ni = 0; ni < 4; ++ni)
                    acc[mi][ni] = mfma_bf16(af[mi], bf[ni], acc[mi][ni]);
        }
        __syncthreads();
    }

    #pragma unroll
    for (int mi = 0; mi < 4; ++mi) {
        #pragma unroll
        for (int r = 0; r < 4; ++r) {
            int rowl = wm + mi * 16 + q * 4 + r;
            if (row0 + rowl < ne) {
                int   tv  = toklds[rowl];
                float wgt = wlds[rowl];
                float* yr = y + (size_t)tv * HD + (nt << 7) + wn + lr;
                #pragma unroll
                for (int ni = 0; ni < 4; ++ni)
                    atomicAdd(yr + ni * 16, wgt * acc[mi][ni][r]);
            }
        }
    }
}

// ---------- launch ----------
extern "C" void kernel_launch(void* const* d_in, const int* in_sizes, int n_in,
                              void* d_out, int out_size, void* d_ws, size_t ws_size,
                              hipStream_t stream) {
    const float* x      = (const float*)d_in[0];
    const float* gw     = (const float*)d_in[1];
    const float* w_gate = (const float*)d_in[2];
    const float* w_up   = (const float*)d_in[3];
    const float* w_down = (const float*)d_in[4];

    float* y      = (float*)d_out;
    float* logits = y + (size_t)NT * HD;

    char* ws = (char*)d_ws;
    const size_t SZ_WT = (size_t)NE * FD * HD * 2;            // 64 MB
    u16* wgT  = (u16*)(ws);                                   // later reused as wdT
    u16* wuT  = (u16*)(ws + SZ_WT);
    u16* xb   = (u16*)(ws + 2 * SZ_WT);
    u16* hbuf = (u16*)(ws + 2 * SZ_WT + (size_t)NT * HD * 2);
    char* tail = ws + 2 * SZ_WT + (size_t)NT * HD * 2 + (size_t)NE * CAP * FD * 2;
    int*   tok = (int*)(tail);
    float* wts = (float*)(tail + (size_t)NE * CAP * 4);
    int*   cnt = (int*)(tail + 2 * (size_t)NE * CAP * 4);

    hipMemsetAsync(d_out, 0, (size_t)out_size * sizeof(float), stream);
    hipMemsetAsync(cnt, 0, 256, stream);

    cvt_x_kernel<<<(NT * HD / 4) / 256, 256, 0, stream>>>(x, xb);
    transpose_cvt<<<dim3((HD / 64) * (FD / 64), NE), 256, 0, stream>>>(w_gate, wgT, HD, FD);
    transpose_cvt<<<dim3((HD / 64) * (FD / 64), NE), 256, 0, stream>>>(w_up,   wuT, HD, FD);
    router_kernel<<<NT, 64, 0, stream>>>(x, gw, logits, tok, wts, cnt);
    gemm_gateup<<<NE * 16 * 16, 256, 0, stream>>>(xb, wgT, wuT, tok, cnt, hbuf);
    // reuse wgT region for transposed w_down (stream-ordered after gemm_gateup)
    transpose_cvt<<<dim3((FD / 64) * (HD / 64), NE), 256, 0, stream>>>(w_down, wgT, FD, HD);
    gemm_down<<<NE * 16 * 16, 256, 0, stream>>>(hbuf, wgT, tok, wts, cnt, y);
}

// Round 2
// 1019.833 us; speedup vs baseline: 1.0444x; 1.0444x over previous
//
#include <hip/hip_runtime.h>
#include <math.h>

typedef unsigned short u16;
typedef unsigned int   u32;
typedef __attribute__((ext_vector_type(8))) short short8;
typedef __attribute__((ext_vector_type(4))) float floatx4;
typedef __attribute__((ext_vector_type(4))) u16   u16x4;

#define NE   16      // experts
#define CAP  2048    // capacity per expert
#define HD   2048    // hidden
#define FD   1024    // intermediate
#define NT   4096    // tokens

// ---------- helpers ----------
__device__ __forceinline__ u16 f2bf(float f) {
    u32 u = __builtin_bit_cast(u32, f);
    u = (u + 0x7FFFu + ((u >> 16) & 1u)) >> 16;   // RNE
    return (u16)u;
}

typedef const u32 __attribute__((address_space(1))) glb_u32;
typedef u32 __attribute__((address_space(3)))       lds_u32;

__device__ __forceinline__ void cp16(const void* g, void* l) {
    __builtin_amdgcn_global_load_lds((glb_u32*)g, (lds_u32*)l, 16, 0, 0);
}

__device__ __forceinline__ floatx4 mfma_bf16(short8 a, short8 b, floatx4 c) {
    return __builtin_amdgcn_mfma_f32_16x16x32_bf16(a, b, c, 0, 0, 0);
}

// ---------- x -> bf16 ----------
__global__ void cvt_x_kernel(const float* __restrict__ x, u16* __restrict__ xb) {
    int i = blockIdx.x * 256 + threadIdx.x;
    float4 v = reinterpret_cast<const float4*>(x)[i];
    u16x4 o; o.x = f2bf(v.x); o.y = f2bf(v.y); o.z = f2bf(v.z); o.w = f2bf(v.w);
    reinterpret_cast<u16x4*>(xb)[i] = o;
}

// ---------- transpose + convert: in [R][Cc] fp32 -> out [Cc][R] bf16 (per expert) ----------
__global__ void transpose_cvt(const float* __restrict__ in, u16* __restrict__ out,
                              int R, int Cc) {
    __shared__ u16 tile[64][65];
    int e = blockIdx.y;
    int tilesC = Cc >> 6;
    int tr = blockIdx.x / tilesC;
    int tc = blockIdx.x - tr * tilesC;
    const float* ip = in + (size_t)e * R * Cc + (size_t)(tr * 64) * Cc + tc * 64;
    u16* op = out + (size_t)e * R * Cc + (size_t)(tc * 64) * R + tr * 64;
    int c  = threadIdx.x & 63;
    int r0 = threadIdx.x >> 6;
    #pragma unroll
    for (int i = 0; i < 16; ++i) {
        int r = r0 + (i << 2);
        tile[r][c] = f2bf(ip[(size_t)r * Cc + c]);
    }
    __syncthreads();
    int rr = threadIdx.x & 63;
    int c0 = threadIdx.x >> 6;
    #pragma unroll
    for (int i = 0; i < 16; ++i) {
        int cc = c0 + (i << 2);
        op[(size_t)cc * R + rr] = tile[rr][cc];
    }
}

// ---------- router: fp64-exact logits, top-4, softmax, dispatch ----------
__global__ void router_kernel(const float* __restrict__ x, const float* __restrict__ gw,
                              float* __restrict__ logits, int* __restrict__ tok,
                              float* __restrict__ wts, int* __restrict__ cnt) {
    int t = blockIdx.x;
    int l = threadIdx.x;      // 0..63
    const float* xr = x + (size_t)t * HD;
    double acc[NE];
    #pragma unroll
    for (int e = 0; e < NE; ++e) acc[e] = 0.0;
    for (int i = 0; i < HD / 64; ++i) {
        float xv = xr[l + (i << 6)];
        const float* g = gw + (size_t)(l + (i << 6)) * NE;
        #pragma unroll
        for (int e = 0; e < NE; ++e) acc[e] += (double)xv * (double)g[e];
    }
    #pragma unroll
    for (int e = 0; e < NE; ++e) {
        double v = acc[e];
        #pragma unroll
        for (int off = 1; off < 64; off <<= 1) v += __shfl_xor(v, off, 64);
        acc[e] = v;
    }
    if (l == 0) {
        #pragma unroll
        for (int e = 0; e < NE; ++e) logits[(size_t)t * NE + e] = (float)acc[e];
        int bi[4]; double bv[4];
        u32 used = 0;
        for (int k = 0; k < 4; ++k) {
            int best = 0; double bvv = -1e300;
            for (int e = 0; e < NE; ++e)
                if (!((used >> e) & 1u) && acc[e] > bvv) { bvv = acc[e]; best = e; }
            bi[k] = best; bv[k] = bvv; used |= 1u << best;
        }
        double s = 0.0, wv[4];
        for (int k = 0; k < 4; ++k) { wv[k] = exp(bv[k] - bv[0]); s += wv[k]; }
        for (int k = 0; k < 4; ++k) {
            int e = bi[k];
            int pos = atomicAdd(&cnt[e], 1);
            if (pos < CAP) {
                tok[e * CAP + pos] = t;
                wts[e * CAP + pos] = (float)(wv[k] / s);
            }
        }
    }
}

// ---------- GEMM1: fused gate+up, 128x(64+64) tile, BK=64, silu epilogue ----------
// LDS layout XOR-swizzled: chunk c of row r lives at slot c^(r&7). The swizzle is
// applied on the GLOBAL source address (global_load_lds dest is pinned to lane*16).
__global__ __launch_bounds__(256) void gemm_gateup(
        const u16* __restrict__ xb, const u16* __restrict__ wgT, const u16* __restrict__ wuT,
        const int* __restrict__ tok, const int* __restrict__ cnt, u16* __restrict__ hbuf) {
    int bid = blockIdx.x;
    int e  = bid >> 8;
    int mt = (bid >> 4) & 15;
    int nt = bid & 15;
    int ne = cnt[e]; if (ne > CAP) ne = CAP;
    int row0 = mt << 7;
    if (row0 >= ne) return;

    __shared__ u16 As[128 * 64];
    __shared__ u16 Bg[64 * 64];
    __shared__ u16 Bu[64 * 64];
    __shared__ int toklds[128];

    int tid = threadIdx.x;
    if (tid < 128) {
        int r = row0 + tid;
        toklds[tid] = tok[e * CAP + (r < ne ? r : 0)];
    }
    __syncthreads();

    const u16* asrc[4];
    #pragma unroll
    for (int p = 0; p < 4; ++p) {
        int idx = tid + (p << 8);
        int r = idx >> 3;
        int c = (idx & 7) ^ (r & 7);            // XOR swizzle
        asrc[p] = xb + (size_t)toklds[r] * HD + (c << 3);
    }
    const u16* bgb = wgT + ((size_t)e * FD + (nt << 6)) * HD;
    const u16* bub = wuT + ((size_t)e * FD + (nt << 6)) * HD;
    const u16* bgsrc[2]; const u16* busrc[2];
    #pragma unroll
    for (int p = 0; p < 2; ++p) {
        int idx = tid + (p << 8);
        int r = idx >> 3;
        int c = (idx & 7) ^ (r & 7);            // XOR swizzle
        bgsrc[p] = bgb + (size_t)r * HD + (c << 3);
        busrc[p] = bub + (size_t)r * HD + (c << 3);
    }

    floatx4 accg[4][2], accu[4][2];
    #pragma unroll
    for (int i = 0; i < 4; ++i)
        #pragma unroll
        for (int j = 0; j < 2; ++j) {
            accg[i][j] = floatx4{0.f, 0.f, 0.f, 0.f};
            accu[i][j] = floatx4{0.f, 0.f, 0.f, 0.f};
        }

    int l = tid & 63, w = tid >> 6;
    int wm = (w >> 1) << 6;   // 0 / 64
    int wn = (w & 1) << 5;    // 0 / 32
    int lr = l & 15, q = l >> 4;
    int sw = lr & 7;          // swizzle key for fragment reads

    for (int k0 = 0; k0 < HD; k0 += 64) {
        #pragma unroll
        for (int p = 0; p < 4; ++p) cp16(asrc[p] + k0, &As[(tid + (p << 8)) << 3]);
        #pragma unroll
        for (int p = 0; p < 2; ++p) {
            cp16(bgsrc[p] + k0, &Bg[(tid + (p << 8)) << 3]);
            cp16(busrc[p] + k0, &Bu[(tid + (p << 8)) << 3]);
        }
        __syncthreads();
        #pragma unroll
        for (int kk = 0; kk < 2; ++kk) {
            int ch = ((kk << 2) + q) ^ sw;      // swizzled chunk
            short8 af[4], bg[2], bu[2];
            #pragma unroll
            for (int mi = 0; mi < 4; ++mi)
                af[mi] = *(const short8*)&As[((wm + mi * 16 + lr) << 6) + (ch << 3)];
            #pragma unroll
            for (int ni = 0; ni < 2; ++ni) {
                bg[ni] = *(const short8*)&Bg[((wn + ni * 16 + lr) << 6) + (ch << 3)];
                bu[ni] = *(const short8*)&Bu[((wn + ni * 16 + lr) << 6) + (ch << 3)];
            }
            #pragma unroll
            for (int mi = 0; mi < 4; ++mi)
                #pragma unroll
                for (int ni = 0; ni < 2; ++ni) {
                    accg[mi][ni] = mfma_bf16(af[mi], bg[ni], accg[mi][ni]);
                    accu[mi][ni] = mfma_bf16(af[mi], bu[ni], accu[mi][ni]);
                }
        }
        __syncthreads();
    }

    // epilogue: h = silu(g)*u, bf16 store
    #pragma unroll
    for (int mi = 0; mi < 4; ++mi) {
        #pragma unroll
        for (int r = 0; r < 4; ++r) {
            int rowl = wm + mi * 16 + q * 4 + r;
            int srow = row0 + rowl;
            if (srow < ne) {
                #pragma unroll
                for (int ni = 0; ni < 2; ++ni) {
                    float g = accg[mi][ni][r], u = accu[mi][ni][r];
                    float hv = g * u / (1.0f + __expf(-g));
                    hbuf[((size_t)e * CAP + srow) * FD + (nt << 6) + wn + ni * 16 + lr] = f2bf(hv);
                }
            }
        }
    }
}

// ---------- GEMM2: down-proj 128x128 tile, BK=64, weighted atomic scatter ----------
__global__ __launch_bounds__(256) void gemm_down(
        const u16* __restrict__ hbuf, const u16* __restrict__ wdT,
        const int* __restrict__ tok, const float* __restrict__ wts,
        const int* __restrict__ cnt, float* __restrict__ y) {
    int bid = blockIdx.x;
    int e  = bid >> 8;
    int mt = (bid >> 4) & 15;
    int nt = bid & 15;
    int ne = cnt[e]; if (ne > CAP) ne = CAP;
    int row0 = mt << 7;
    if (row0 >= ne) return;

    __shared__ u16 As[128 * 64];
    __shared__ u16 Bs[128 * 64];
    __shared__ int   toklds[128];
    __shared__ float wlds[128];

    int tid = threadIdx.x;
    if (tid < 128) {
        int r = row0 + tid;
        int ok = (r < ne);
        toklds[tid] = ok ? tok[e * CAP + r] : 0;
        wlds[tid]  = ok ? wts[e * CAP + r] : 0.0f;
    }

    const u16* ab = hbuf + ((size_t)e * CAP + row0) * FD;
    const u16* bb = wdT + ((size_t)e * HD + (nt << 7)) * FD;
    const u16* asrc[4]; const u16* bsrc[4];
    #pragma unroll
    for (int p = 0; p < 4; ++p) {
        int idx = tid + (p << 8);
        int r = idx >> 3;
        int c = (idx & 7) ^ (r & 7);            // XOR swizzle
        asrc[p] = ab + (size_t)r * FD + (c << 3);
        bsrc[p] = bb + (size_t)r * FD + (c << 3);
    }

    floatx4 acc[4][4];
    #pragma unroll
    for (int i = 0; i < 4; ++i)
        #pragma unroll
        for (int j = 0; j < 4; ++j) acc[i][j] = floatx4{0.f, 0.f, 0.f, 0.f};

    int l = tid & 63, w = tid >> 6;
    int wm = (w >> 1) << 6;
    int wn = (w & 1) << 6;
    int lr = l & 15, q = l >> 4;
    int sw = lr & 7;

    for (int k0 = 0; k0 < FD; k0 += 64) {
        #pragma unroll
        for (int p = 0; p < 4; ++p) {
            cp16(asrc[p] + k0, &As[(tid + (p << 8)) << 3]);
            cp16(bsrc[p] + k0, &Bs[(tid + (p << 8)) << 3]);
        }
        __syncthreads();
        #pragma unroll
        for (int kk = 0; kk < 2; ++kk) {
            int ch = ((kk << 2) + q) ^ sw;
            short8 af[4], bf[4];
            #pragma unroll
            for (int mi = 0; mi < 4; ++mi)
                af[mi] = *(const short8*)&As[((wm + mi * 16 + lr) << 6) + (ch << 3)];
            #pragma unroll
            for (int ni = 0; ni < 4; ++ni)
                bf[ni] = *(const short8*)&Bs[((wn + ni * 16 + lr) << 6) + (ch << 3)];
            #pragma unroll
            for (int mi = 0; mi < 4; ++mi)
                #pragma unroll
                for (int ni = 0; ni < 4; ++ni)
                    acc[mi][ni] = mfma_bf16(af[mi], bf[ni], acc[mi][ni]);
        }
        __syncthreads();
    }

    #pragma unroll
    for (int mi = 0; mi < 4; ++mi) {
        #pragma unroll
        for (int r = 0; r < 4; ++r) {
            int rowl = wm + mi * 16 + q * 4 + r;
            if (row0 + rowl < ne) {
                int   tv  = toklds[rowl];
                float wgt = wlds[rowl];
                float* yr = y + (size_t)tv * HD + (nt << 7) + wn + lr;
                #pragma unroll
                for (int ni = 0; ni < 4; ++ni)
                    atomicAdd(yr + ni * 16, wgt * acc[mi][ni][r]);
            }
        }
    }
}

// ---------- launch ----------
extern "C" void kernel_launch(void* const* d_in, const int* in_sizes, int n_in,
                              void* d_out, int out_size, void* d_ws, size_t ws_size,
                              hipStream_t stream) {
    const float* x      = (const float*)d_in[0];
    const float* gw     = (const float*)d_in[1];
    const float* w_gate = (const float*)d_in[2];
    const float* w_up   = (const float*)d_in[3];
    const float* w_down = (const float*)d_in[4];

    float* y      = (float*)d_out;
    float* logits = y + (size_t)NT * HD;

    char* ws = (char*)d_ws;
    const size_t SZ_WT = (size_t)NE * FD * HD * 2;            // 64 MB
    u16* wgT  = (u16*)(ws);                                   // later reused as wdT
    u16* wuT  = (u16*)(ws + SZ_WT);
    u16* xb   = (u16*)(ws + 2 * SZ_WT);
    u16* hbuf = (u16*)(ws + 2 * SZ_WT + (size_t)NT * HD * 2);
    char* tail = ws + 2 * SZ_WT + (size_t)NT * HD * 2 + (size_t)NE * CAP * FD * 2;
    int*   tok = (int*)(tail);
    float* wts = (float*)(tail + (size_t)NE * CAP * 4);
    int*   cnt = (int*)(tail + 2 * (size_t)NE * CAP * 4);

    hipMemsetAsync(d_out, 0, (size_t)out_size * sizeof(float), stream);
    hipMemsetAsync(cnt, 0, 256, stream);

    cvt_x_kernel<<<(NT * HD / 4) / 256, 256, 0, stream>>>(x, xb);
    transpose_cvt<<<dim3((HD / 64) * (FD / 64), NE), 256, 0, stream>>>(w_gate, wgT, HD, FD);
    transpose_cvt<<<dim3((HD / 64) * (FD / 64), NE), 256, 0, stream>>>(w_up,   wuT, HD, FD);
    router_kernel<<<NT, 64, 0, stream>>>(x, gw, logits, tok, wts, cnt);
    gemm_gateup<<<NE * 16 * 16, 256, 0, stream>>>(xb, wgT, wuT, tok, cnt, hbuf);
    // reuse wgT region for transposed w_down (stream-ordered after gemm_gateup)
    transpose_cvt<<<dim3((FD / 64) * (HD / 64), NE), 256, 0, stream>>>(w_down, wgT, FD, HD);
    gemm_down<<<NE * 16 * 16, 256, 0, stream>>>(hbuf, wgT, tok, wts, cnt, y);
}